// Round 15
// baseline (2372.103 us; speedup 1.0000x reference)
//
#include <hip/hip_runtime.h>
#include <cstdint>
#include <math.h>

typedef unsigned short u16;
typedef __attribute__((ext_vector_type(4))) float f32x4;
typedef __attribute__((ext_vector_type(8))) __bf16 bf16x8;
typedef __attribute__((ext_vector_type(8))) short short8;

typedef __attribute__((address_space(1))) void g_void;
typedef __attribute__((address_space(3))) void l_void;

__device__ __forceinline__ u16 f2bf(float f) {
  uint32_t u = __builtin_bit_cast(uint32_t, f);
  u += 0x7FFFu + ((u >> 16) & 1u);
  return (u16)(u >> 16);
}
__device__ __forceinline__ float bf2f(u16 h) {
  uint32_t u = ((uint32_t)h) << 16;
  return __builtin_bit_cast(float, u);
}

__device__ __forceinline__ void gload16(const void* g, void* l) {
  __builtin_amdgcn_global_load_lds((g_void*)g, (l_void*)l, 16, 0, 0);
}

// branchless GELU: erf via A&S 7.1.26 (max abs err 1.5e-7)
__device__ __forceinline__ float gelu_exact(float x) {
  float a = x * 0.70710678118654752f;
  float s = fabsf(a);
  float t = __builtin_amdgcn_rcpf(fmaf(0.3275911f, s, 1.0f));
  float p = fmaf(fmaf(fmaf(fmaf(1.061405429f, t, -1.453152027f), t, 1.421413741f), t,
                      -0.284496736f), t, 0.254829592f);
  p *= t;
  float e = __expf(-s * s);
  float er = fmaf(-p, e, 1.0f);
  er = copysignf(er, a);
  return 0.5f * x * (1.0f + er);
}

// ---------------- weight transpose + bf16 convert: Wt[n][k] = W[k][n] ----------------
__global__ void transpose_w(const float* __restrict__ W, u16* __restrict__ Wt, int K, int N) {
  __shared__ float t[32][33];
  const int nb = blockIdx.x * 32, kb = blockIdx.y * 32;
  const int tx = threadIdx.x, ty = threadIdx.y;
#pragma unroll
  for (int i = 0; i < 32; i += 8)
    t[ty + i][tx] = W[(size_t)(kb + ty + i) * N + nb + tx];
  __syncthreads();
#pragma unroll
  for (int i = 0; i < 32; i += 8)
    Wt[(size_t)(nb + ty + i) * K + kb + tx] = f2bf(t[tx][ty + i]);
}

// ---------------- embedding (bf16 residual stream) ----------------
__global__ void embed_k(const int* __restrict__ z, const int* __restrict__ hgs,
                        const float* __restrict__ ae, const float* __restrict__ ne,
                        u16* __restrict__ xb) {
  const int row = blockIdx.x;
  const int b = row >> 7, tl = row & 127;
  int ia = 1, in_ = 0;
  if (tl > 0) { ia = z[b * 127 + tl - 1] + 2; in_ = hgs[b * 127 + tl - 1] + 2; }
  const float* ar = ae + (size_t)ia * 1024;
  const float* nr = ne + (size_t)in_ * 1024;
  for (int c = threadIdx.x; c < 1024; c += 256)
    xb[(size_t)row * 1024 + c] = f2bf(ar[c] + nr[c]);
}

// ------- attention bias mask*8 precompute, layout [bh][col lk:128][row lq:128] bf16 -----
__global__ void mask_k(const float* __restrict__ pos, const float* __restrict__ demb,
                       u16* __restrict__ mask) {
  __shared__ float edges[85];
  __shared__ float dhT[16 * 86];  // [h][c], pre-scaled by 8
  const int blk = blockIdx.x;
  const int b = blk >> 7, lk = blk & 127;
  const int lq = threadIdx.x;  // 128 threads
  if (lq < 85) {
    double e = 0.75 + 0.05 * (double)lq;
    float ef = (float)e;
    if (lq == 0) ef = -1.0f; else if (lq == 1) ef = 0.0f; else if (lq == 2) ef = 0.01f;
    edges[lq] = ef;
  }
  for (int i = lq; i < 16 * 86; i += 128) {
    const int h = i / 86, c = i - h * 86;
    float v = (c == 0) ? -INFINITY : demb[c * 16 + h] * 8.0f;
    dhT[i] = v;
  }
  __syncthreads();
  int c;
  if (lq == 0 || lk == 0) {
    c = 1;
  } else {
    const float* pi = pos + ((size_t)b * 127 + lq - 1) * 3;
    const float* pj = pos + ((size_t)b * 127 + lk - 1) * 3;
    const float dx = pi[0] - pj[0], dy = pi[1] - pj[1], dz = pi[2] - pj[2];
    const float d = sqrtf(dx * dx + dy * dy + dz * dz);
    int cnt = 0;
#pragma unroll
    for (int k2 = 0; k2 < 85; ++k2) cnt += (edges[k2] <= d) ? 1 : 0;
    c = cnt;
  }
#pragma unroll
  for (int h = 0; h < 16; ++h)
    mask[((size_t)(b * 16 + h) << 14) + lk * 128 + lq] = f2bf(dhT[h * 86 + c]);
}

// ------- 8-phase big GEMM: 256x256, BK=64, 8 waves (2Mx4N), wave-tile 128x64 ----------
// LDS 128KB: A/B x 2buf x 2kk x 16KB slabs ([256 rows][32 K] bf16, st-swizzled).
// Per K-tile: 4 phases {vmcnt(ph0/2) ; ds_reads ; stage 1 slab ; barrier ; lgkm0 ;
// setprio + 16 MFMA ; barrier}. Invariant: at t.ph0 outstanding = tile t's 4 slabs (8
// gloads) -> vmcnt(4) completes the 2 slabs phases 0-1 read; same at ph2.
// MODE 0: qkv scatter -> Q(B,H,L,d) K(B,H,L,d) V(B,H,d,L)   MODE 2: gelu bf16
template <int MODE>
__launch_bounds__(512, 2)
__global__ void gemm8p(const u16* __restrict__ A, const u16* __restrict__ Bt,
                       const float* __restrict__ bias,
                       u16* __restrict__ O0, u16* __restrict__ O1, u16* __restrict__ O2,
                       int N, int K) {
  extern __shared__ char lds[];
  const int tid = threadIdx.x;
  const int w = tid >> 6, l = tid & 63;
  const int wr = w >> 2, wc = w & 3;  // 2M x 4N
  const int nwg = gridDim.x;
  const int wg = (blockIdx.x & 7) * (nwg >> 3) + (blockIdx.x >> 3);
  const int ntn = N >> 8;
  const int bm = wg / ntn, bn = wg - (wg / ntn) * ntn;
  const int NT = K >> 6;

  const int colc = ((((l & 3) << 4) ^ (((l >> 2) & 8) << 2)) >> 1);
  const u16* Ag = A + (size_t)(bm * 256 + w * 16 + (l >> 2)) * K + colc;
  const u16* Bg = Bt + (size_t)(bn * 256 + w * 16 + (l >> 2)) * K + colc;
  const int ldst = w << 10;

  auto slab = [&](int op, int buf, int kk) -> char* {
    return lds + op * 65536 + (((buf << 1) | kk) << 14);
  };
  auto stA = [&](int t, int kk) {
    char* s = slab(0, t & 1, kk);
    const int kb = t * 64 + kk * 32;
    gload16(Ag + kb, s + ldst);
    gload16(Ag + (size_t)128 * K + kb, s + 8192 + ldst);
  };
  auto stB = [&](int t, int kk) {
    char* s = slab(1, t & 1, kk);
    const int kb = t * 64 + kk * 32;
    gload16(Bg + kb, s + ldst);
    gload16(Bg + (size_t)128 * K + kb, s + 8192 + ldst);
  };

  const int lo = ((l & 15) << 6) + (((l >> 4) << 4) ^ ((l & 8) << 2));

  f32x4 acc[8][4];
#pragma unroll
  for (int m = 0; m < 8; ++m)
#pragma unroll
    for (int n = 0; n < 4; ++n) acc[m][n] = f32x4{0.f, 0.f, 0.f, 0.f};

  // prologue: tile 0 fully staged, drained
  stA(0, 0); stB(0, 0); stA(0, 1); stB(0, 1);
  asm volatile("s_waitcnt vmcnt(0)" ::: "memory");
  __builtin_amdgcn_s_barrier();

  for (int t = 0; t < NT; ++t) {
    const int p = t & 1;
    const bool pre = (t + 1 < NT);
    const char* sa0 = slab(0, p, 0) + (wr << 13);
    const char* sa1 = slab(0, p, 1) + (wr << 13);
    const char* sb0 = slab(1, p, 0) + (wc << 12);
    const char* sb1 = slab(1, p, 1) + (wc << 12);
    bf16x8 af[4], bf[4];

    // ---- phase 0: (mh0, kk0); stage A0(t+1) ----
    asm volatile("s_waitcnt vmcnt(4)" ::: "memory");
#pragma unroll
    for (int m = 0; m < 4; ++m) af[m] = *(const bf16x8*)(sa0 + (m << 10) + lo);
#pragma unroll
    for (int n = 0; n < 4; ++n) bf[n] = *(const bf16x8*)(sb0 + (n << 10) + lo);
    if (pre) stA(t + 1, 0);
    __builtin_amdgcn_s_barrier();
    asm volatile("s_waitcnt lgkmcnt(0)" ::: "memory");
    __builtin_amdgcn_s_setprio(1);
#pragma unroll
    for (int m = 0; m < 4; ++m)
#pragma unroll
      for (int n = 0; n < 4; ++n)
        acc[m][n] = __builtin_amdgcn_mfma_f32_16x16x32_bf16(af[m], bf[n], acc[m][n], 0, 0, 0);
    __builtin_amdgcn_s_setprio(0);
    __builtin_amdgcn_s_barrier();

    // ---- phase 1: (mh1, kk0) — B kk0 frags persist in regs; stage B0(t+1) ----
#pragma unroll
    for (int m = 0; m < 4; ++m) af[m] = *(const bf16x8*)(sa0 + ((m + 4) << 10) + lo);
    if (pre) stB(t + 1, 0);
    __builtin_amdgcn_s_barrier();
    asm volatile("s_waitcnt lgkmcnt(0)" ::: "memory");
    __builtin_amdgcn_s_setprio(1);
#pragma unroll
    for (int m = 0; m < 4; ++m)
#pragma unroll
      for (int n = 0; n < 4; ++n)
        acc[m + 4][n] = __builtin_amdgcn_mfma_f32_16x16x32_bf16(af[m], bf[n], acc[m + 4][n], 0, 0, 0);
    __builtin_amdgcn_s_setprio(0);
    __builtin_amdgcn_s_barrier();

    // ---- phase 2: (mh0, kk1); stage A1(t+1) ----
    if (pre) asm volatile("s_waitcnt vmcnt(4)" ::: "memory");
    else     asm volatile("s_waitcnt vmcnt(0)" ::: "memory");
#pragma unroll
    for (int m = 0; m < 4; ++m) af[m] = *(const bf16x8*)(sa1 + (m << 10) + lo);
#pragma unroll
    for (int n = 0; n < 4; ++n) bf[n] = *(const bf16x8*)(sb1 + (n << 10) + lo);
    if (pre) stA(t + 1, 1);
    __builtin_amdgcn_s_barrier();
    asm volatile("s_waitcnt lgkmcnt(0)" ::: "memory");
    __builtin_amdgcn_s_setprio(1);
#pragma unroll
    for (int m = 0; m < 4; ++m)
#pragma unroll
      for (int n = 0; n < 4; ++n)
        acc[m][n] = __builtin_amdgcn_mfma_f32_16x16x32_bf16(af[m], bf[n], acc[m][n], 0, 0, 0);
    __builtin_amdgcn_s_setprio(0);
    __builtin_amdgcn_s_barrier();

    // ---- phase 3: (mh1, kk1); stage B1(t+1) ----
#pragma unroll
    for (int m = 0; m < 4; ++m) af[m] = *(const bf16x8*)(sa1 + ((m + 4) << 10) + lo);
    if (pre) stB(t + 1, 1);
    __builtin_amdgcn_s_barrier();
    asm volatile("s_waitcnt lgkmcnt(0)" ::: "memory");
    __builtin_amdgcn_s_setprio(1);
#pragma unroll
    for (int m = 0; m < 4; ++m)
#pragma unroll
      for (int n = 0; n < 4; ++n)
        acc[m + 4][n] = __builtin_amdgcn_mfma_f32_16x16x32_bf16(af[m], bf[n], acc[m + 4][n], 0, 0, 0);
    __builtin_amdgcn_s_setprio(0);
    __builtin_amdgcn_s_barrier();
  }

  // epilogue: wave rows [wr*128, +128), cols [wc*64, +64)
  const int fr = l & 15, fq = l >> 4;
  const int colb = bn * 256 + wc * 64;
  const int rowb = bm * 256 + wr * 128;
  float bv[4];
#pragma unroll
  for (int n = 0; n < 4; ++n) bv[n] = bias[colb + n * 16 + fr];
  const int region = colb >> 10;

#pragma unroll
  for (int m = 0; m < 8; ++m) {
#pragma unroll
    for (int n = 0; n < 4; ++n) {
      const int col = colb + n * 16 + fr;
      if (MODE == 0 && region == 2) {
        const int row0_ = rowb + m * 16 + fq * 4;
        const int bI = row0_ >> 7, tl0 = row0_ & 127;
        const int c = col & 1023, h = c >> 6, d = c & 63;
        ushort4 pk;
        pk.x = f2bf(acc[m][n][0] + bv[n]);
        pk.y = f2bf(acc[m][n][1] + bv[n]);
        pk.z = f2bf(acc[m][n][2] + bv[n]);
        pk.w = f2bf(acc[m][n][3] + bv[n]);
        *(ushort4*)&O2[(((size_t)bI * 16 + h) * 64 + d) * 128 + tl0] = pk;
      } else {
#pragma unroll
        for (int j = 0; j < 4; ++j) {
          const int row = rowb + m * 16 + fq * 4 + j;
          float v = acc[m][n][j] + bv[n];
          if (MODE == 2) v = gelu_exact(v);
          if (MODE == 0) {
            const int bI = row >> 7, tl = row & 127;
            const int c = col & 1023, h = c >> 6, d = c & 63;
            if (region == 0) O0[(((size_t)bI * 16 + h) * 128 + tl) * 64 + d] = f2bf(v);
            else             O1[(((size_t)bI * 16 + h) * 128 + tl) * 64 + d] = f2bf(v);
          } else {
            O0[(size_t)row * N + col] = f2bf(v);
          }
        }
      }
    }
  }
}

// ------- small GEMM (N=1024): ring-4 depth-3 (R12-proven) ------------
__launch_bounds__(256, 2)
__global__ void gemm4r(const u16* __restrict__ A, const u16* __restrict__ Bt,
                       const float* __restrict__ bias, u16* __restrict__ O,
                       int N, int K) {
  extern __shared__ char lds[];
  const int tid = threadIdx.x;
  const int w = tid >> 6, l = tid & 63;
  const int wr = w >> 1, wc = w & 1;
  const int nwg = gridDim.x;
  const int wg = (blockIdx.x & 7) * (nwg >> 3) + (blockIdx.x >> 3);
  const int ntn = N >> 7;
  const int bm = wg / ntn, bn = wg - (wg / ntn) * ntn;
  const int NT = K >> 5;  // 32 or 96, divisible by 4

  const int colc = ((((l & 3) << 4) ^ (((l >> 2) & 8) << 2)) >> 1);
  const u16* Ag = A + (size_t)(bm * 128 + w * 16 + (l >> 2)) * K + colc;
  const u16* Bg = Bt + (size_t)(bn * 128 + w * 16 + (l >> 2)) * K + colc;
  const int ldst = w << 10;

  auto stage = [&](int t) {
    char* buf = lds + ((t & 3) << 14);
    const int kb = t << 5;
    gload16(Ag + kb, buf + ldst);
    gload16(Ag + (size_t)64 * K + kb, buf + 4096 + ldst);
    gload16(Bg + kb, buf + 8192 + ldst);
    gload16(Bg + (size_t)64 * K + kb, buf + 12288 + ldst);
  };

  const int lo = ((l & 15) << 6) + (((l >> 4) << 4) ^ ((l & 8) << 2));

  f32x4 acc[4][4];
#pragma unroll
  for (int m = 0; m < 4; ++m)
#pragma unroll
    for (int n = 0; n < 4; ++n) acc[m][n] = f32x4{0.f, 0.f, 0.f, 0.f};

  auto compute = [&](int bi) {
    const char* ab = lds + (bi << 14) + (wr << 12);
    const char* bb = lds + (bi << 14) + 8192 + (wc << 12);
    bf16x8 af[4], bf[4];
#pragma unroll
    for (int m = 0; m < 4; ++m) af[m] = *(const bf16x8*)(ab + (m << 10) + lo);
#pragma unroll
    for (int n = 0; n < 4; ++n) bf[n] = *(const bf16x8*)(bb + (n << 10) + lo);
    __builtin_amdgcn_s_setprio(1);
#pragma unroll
    for (int m = 0; m < 4; ++m)
#pragma unroll
      for (int n = 0; n < 4; ++n)
        acc[m][n] = __builtin_amdgcn_mfma_f32_16x16x32_bf16(af[m], bf[n], acc[m][n], 0, 0, 0);
    __builtin_amdgcn_s_setprio(0);
  };

  stage(0); stage(1); stage(2);
  asm volatile("s_waitcnt vmcnt(8)" ::: "memory");
  __builtin_amdgcn_s_barrier();

  for (int t4 = 0; t4 + 4 < NT; t4 += 4) {
#pragma unroll
    for (int u = 0; u < 4; ++u) {
      stage(t4 + u + 3);
      compute(u);
      asm volatile("s_waitcnt vmcnt(8)" ::: "memory");
      __builtin_amdgcn_s_barrier();
    }
  }
  stage(NT - 1);
  compute(0);
  asm volatile("s_waitcnt vmcnt(8)" ::: "memory");
  __builtin_amdgcn_s_barrier();
  compute(1);
  asm volatile("s_waitcnt vmcnt(4)" ::: "memory");
  __builtin_amdgcn_s_barrier();
  compute(2);
  asm volatile("s_waitcnt vmcnt(0)" ::: "memory");
  __builtin_amdgcn_s_barrier();
  compute(3);

  const int fr = l & 15, fq = l >> 4;
  const int colb = bn * 128 + wc * 64;
  const int rowb = bm * 128 + wr * 64;
  float bv[4];
#pragma unroll
  for (int n = 0; n < 4; ++n) bv[n] = bias[colb + n * 16 + fr];
#pragma unroll
  for (int m = 0; m < 4; ++m)
#pragma unroll
    for (int n = 0; n < 4; ++n) {
      const int col = colb + n * 16 + fr;
#pragma unroll
      for (int j = 0; j < 4; ++j) {
        const int row = rowb + m * 16 + fq * 4 + j;
        O[(size_t)row * N + col] = f2bf(acc[m][n][j] + bv[n]);
      }
    }
}

// ------ fused attention: one block per (b,h); mask*8 as QK^T acc-init ------
__launch_bounds__(256)
__global__ void attn_kernel(const u16* __restrict__ Qg, const u16* __restrict__ Kg,
                            const u16* __restrict__ Vg,
                            const u16* __restrict__ mask,
                            u16* __restrict__ Og) {
  __shared__ u16 QK[2 * 128 * 64];
  __shared__ u16 Vt[64 * 128];
  const int tid = threadIdx.x;
  const int wv = tid >> 6;
  const int l = tid & 63;
  const int bh = blockIdx.x;
  const int b = bh >> 4;

  const char* Qs = (const char*)(Qg + (size_t)bh * 8192);
  const char* Ks = (const char*)(Kg + (size_t)bh * 8192);
  const char* Vs = (const char*)(Vg + (size_t)bh * 8192);
  char* QKb = (char*)QK;
  char* Vtb = (char*)Vt;
#pragma unroll
  for (int it = 0; it < 4; ++it) {
    const int r = it * 32 + (tid >> 3);
    const int cb = (tid & 7) * 16;
    const int sw = cb ^ ((r & 7) << 4);
    *(uint4*)(QKb + r * 128 + sw) = *(const uint4*)(Qs + r * 128 + cb);
    *(uint4*)(QKb + 16384 + r * 128 + sw) = *(const uint4*)(Ks + r * 128 + cb);
  }
#pragma unroll
  for (int it = 0; it < 4; ++it) {
    const int r = it * 16 + (tid >> 4);
    const int cb = (tid & 15) * 16;
    const int sw = cb ^ ((r & 7) << 4);
    *(uint4*)(Vtb + r * 256 + sw) = *(const uint4*)(Vs + r * 256 + cb);
  }

  const u16* m8 = mask + ((size_t)bh << 14);
  f32x4 s[2][8];
#pragma unroll
  for (int m = 0; m < 2; ++m) {
    const int r0 = wv * 32 + m * 16 + (l >> 4) * 4;
#pragma unroll
    for (int n = 0; n < 8; ++n) {
      const int col = n * 16 + (l & 15);
      const ushort4 mv = *(const ushort4*)(m8 + col * 128 + r0);
      s[m][n] = f32x4{bf2f(mv.x), bf2f(mv.y), bf2f(mv.z), bf2f(mv.w)};
    }
  }
  __syncthreads();

#pragma unroll
  for (int kk = 0; kk < 2; ++kk) {
    bf16x8 qa[2], kb[8];
#pragma unroll
    for (int m = 0; m < 2; ++m) {
      const int qr = wv * 32 + m * 16 + (l & 15);
      qa[m] = *(const bf16x8*)(QKb + qr * 128 + ((kk * 64 + (l >> 4) * 16) ^ ((qr & 7) << 4)));
    }
#pragma unroll
    for (int n = 0; n < 8; ++n) {
      const int kr = n * 16 + (l & 15);
      kb[n] = *(const bf16x8*)(QKb + 16384 + kr * 128 + ((kk * 64 + (l >> 4) * 16) ^ ((kr & 7) << 4)));
    }
#pragma unroll
    for (int m = 0; m < 2; ++m)
#pragma unroll
      for (int n = 0; n < 8; ++n)
        s[m][n] = __builtin_amdgcn_mfma_f32_16x16x32_bf16(qa[m], kb[n], s[m][n], 0, 0, 0);
  }

  float rinv[2][4];
#pragma unroll
  for (int m = 0; m < 2; ++m) {
#pragma unroll
    for (int j = 0; j < 4; ++j) {
      float vals[8];
#pragma unroll
      for (int n = 0; n < 8; ++n)
        vals[n] = s[m][n][j] * 0.125f;
      float mx = vals[0];
#pragma unroll
      for (int n = 1; n < 8; ++n) mx = fmaxf(mx, vals[n]);
#pragma unroll
      for (int o = 1; o < 16; o <<= 1) mx = fmaxf(mx, __shfl_xor(mx, o, 64));
      float sum = 0.f;
#pragma unroll
      for (int n = 0; n < 8; ++n) { vals[n] = expf(vals[n] - mx); sum += vals[n]; }
#pragma unroll
      for (int o = 1; o < 16; o <<= 1) sum += __shfl_xor(sum, o, 64);
      rinv[m][j] = 1.f / sum;
#pragma unroll
      for (int n = 0; n < 8; ++n) s[m][n][j] = vals[n];
    }
  }
  __syncthreads();
  char* Pb = QKb + wv * 8192;
#pragma unroll
  for (int m = 0; m < 2; ++m)
#pragma unroll
    for (int n = 0; n < 8; ++n)
#pragma unroll
      for (int j = 0; j < 4; ++j) {
        const int pr = m * 16 + (l >> 4) * 4 + j;
        const int pc = (n * 16 + (l & 15)) * 2;
        *(u16*)(Pb + pr * 256 + (pc ^ ((pr & 7) << 4))) = f2bf(s[m][n][j]);
      }

  f32x4 o_[2][4];
#pragma unroll
  for (int m = 0; m < 2; ++m)
#pragma unroll
    for (int n = 0; n < 4; ++n) o_[m][n] = f32x4{0.f, 0.f, 0.f, 0.f};
#pragma unroll
  for (int ks = 0; ks < 4; ++ks) {
    bf16x8 pa[2], vb[4];
#pragma unroll
    for (int m = 0; m < 2; ++m) {
      const int pr = m * 16 + (l & 15);
      pa[m] = *(const bf16x8*)(Pb + pr * 256 + ((ks * 64 + (l >> 4) * 16) ^ ((pr & 7) << 4)));
    }
#pragma unroll
    for (int n = 0; n < 4; ++n) {
      const int vr = n * 16 + (l & 15);
      vb[n] = *(const bf16x8*)(Vtb + vr * 256 + ((ks * 64 + (l >> 4) * 16) ^ ((vr & 7) << 4)));
    }
#pragma unroll
    for (int m = 0; m < 2; ++m)
#pragma unroll
      for (int n = 0; n < 4; ++n)
        o_[m][n] = __builtin_amdgcn_mfma_f32_16x16x32_bf16(pa[m], vb[n], o_[m][n], 0, 0, 0);
  }
  const int h = bh & 15;
#pragma unroll
  for (int m = 0; m < 2; ++m)
#pragma unroll
    for (int n = 0; n < 4; ++n)
#pragma unroll
      for (int j = 0; j < 4; ++j) {
        const int lo2 = wv * 32 + m * 16 + (l >> 4) * 4 + j;
        const int d = n * 16 + (l & 15);
        Og[((size_t)b * 128 + lo2) * 1024 + h * 64 + d] = f2bf(o_[m][n][j] * rinv[m][j]);
      }
}

// ---------------- residual + LayerNorm, bf16 stream, vectorized ----------------
__launch_bounds__(256)
__global__ void ln_res(u16* __restrict__ xb, const u16* __restrict__ o,
                       const float* __restrict__ gam, const float* __restrict__ bet,
                       float* __restrict__ cls_out) {
  const int row = blockIdx.x * 4 + (threadIdx.x >> 6);
  const int l = threadIdx.x & 63;
  const size_t base = (size_t)row * 1024 + l * 16;
  const int c0 = l * 16;
  float v[16], gv[16], bb[16];
  const short8 xa = *(const short8*)(xb + base);
  const short8 xc = *(const short8*)(xb + base + 8);
  const short8 oa = *(const short8*)(o + base);
  const short8 oc = *(const short8*)(o + base + 8);
#pragma unroll
  for (int i = 0; i < 4; ++i) {
    *(float4*)&gv[i * 4] = *(const float4*)(gam + c0 + i * 4);
    *(float4*)&bb[i * 4] = *(const float4*)(bet + c0 + i * 4);
  }
  float s = 0.f, sq = 0.f;
#pragma unroll
  for (int i = 0; i < 8; ++i) {
    v[i] = bf2f((u16)xa[i]) + bf2f((u16)oa[i]);
    v[i + 8] = bf2f((u16)xc[i]) + bf2f((u16)oc[i]);
  }
#pragma unroll
  for (int i = 0; i < 16; ++i) { s += v[i]; sq += v[i] * v[i]; }
#pragma unroll
  for (int off = 1; off < 64; off <<= 1) {
    s += __shfl_xor(s, off, 64);
    sq += __shfl_xor(sq, off, 64);
  }
  const float mean = s * (1.f / 1024.f);
  const float var = sq * (1.f / 1024.f) - mean * mean;
  const float rstd = rsqrtf(var + 1e-5f);
  short8 ra, rc;
#pragma unroll
  for (int i = 0; i < 8; ++i) {
    const float ya = (v[i] - mean) * rstd * gv[i] + bb[i];
    const float yc = (v[i + 8] - mean) * rstd * gv[i + 8] + bb[i + 8];
    ra[i] = (short)f2bf(ya);
    rc[i] = (short)f2bf(yc);
    if ((row & 127) == 0) {
      cls_out[(size_t)(row >> 7) * 1024 + c0 + i] = ya;
      cls_out[(size_t)(row >> 7) * 1024 + c0 + 8 + i] = yc;
    }
  }
  *(short8*)(xb + base) = ra;
  *(short8*)(xb + base + 8) = rc;
}

extern "C" void kernel_launch(void* const* d_in, const int* in_sizes, int n_in,
                              void* d_out, int out_size, void* d_ws, size_t ws_size,
                              hipStream_t stream) {
  const int* z = (const int*)d_in[0];
  const int* hgs = (const int*)d_in[1];
  const float* pos = (const float*)d_in[2];
  const float* atoms_emb = (const float*)d_in[4];
  const float* neigh_emb = (const float*)d_in[5];
  const float* dist_emb = (const float*)d_in[6];
  const float* Wqkv = (const float*)d_in[7];
  const float* bqkv = (const float*)d_in[8];
  const float* Wo = (const float*)d_in[9];
  const float* bo = (const float*)d_in[10];
  const float* W1 = (const float*)d_in[11];
  const float* b1f = (const float*)d_in[12];
  const float* W2 = (const float*)d_in[13];
  const float* b2f = (const float*)d_in[14];
  const float* ln1g = (const float*)d_in[15];
  const float* ln1b = (const float*)d_in[16];
  const float* ln2g = (const float*)d_in[17];
  const float* ln2b = (const float*)d_in[18];

  size_t off = 0;
  char* wsb = (char*)d_ws;
  auto alc = [&](size_t bytes) { void* p = wsb + off; off += (bytes + 255) & ~(size_t)255; return p; };
  u16* xb = (u16*)alc(8192ull * 1024 * 2);
  u16* q = (u16*)alc(8192ull * 1024 * 2);
  u16* k = (u16*)alc(8192ull * 1024 * 2);
  u16* v = (u16*)alc(8192ull * 1024 * 2);
  u16* proj = (u16*)alc(8192ull * 1024 * 2);
  u16* big = (u16*)alc(8192ull * 3072 * 2);
  u16* wqkvt = (u16*)alc(3072ull * 1024 * 2);
  u16* wot = (u16*)alc(1024ull * 1024 * 2);
  u16* w1t = (u16*)alc(3072ull * 1024 * 2);
  u16* w2t = (u16*)alc(1024ull * 3072 * 2);
  u16* mask = (u16*)alc(64ull * 16 * 128 * 128 * 2);

  hipFuncSetAttribute((const void*)gemm8p<0>, hipFuncAttributeMaxDynamicSharedMemorySize, 131072);
  hipFuncSetAttribute((const void*)gemm8p<2>, hipFuncAttributeMaxDynamicSharedMemorySize, 131072);
  hipFuncSetAttribute((const void*)gemm4r, hipFuncAttributeMaxDynamicSharedMemorySize, 65536);

  transpose_w<<<dim3(96, 32), dim3(32, 8), 0, stream>>>(Wqkv, wqkvt, 1024, 3072);
  transpose_w<<<dim3(32, 32), dim3(32, 8), 0, stream>>>(Wo, wot, 1024, 1024);
  transpose_w<<<dim3(96, 32), dim3(32, 8), 0, stream>>>(W1, w1t, 1024, 3072);
  transpose_w<<<dim3(32, 96), dim3(32, 8), 0, stream>>>(W2, w2t, 3072, 1024);
  embed_k<<<8192, 256, 0, stream>>>(z, hgs, atoms_emb, neigh_emb, xb);
  mask_k<<<8192, 128, 0, stream>>>(pos, dist_emb, mask);

  float* cls = (float*)d_out;
  for (int layer = 0; layer < 8; ++layer) {
    gemm8p<0><<<384, 512, 131072, stream>>>(xb, wqkvt, bqkv, q, k, v, 3072, 1024);
    attn_kernel<<<1024, 256, 0, stream>>>(q, k, v, mask, big);
    gemm4r<<<512, 256, 65536, stream>>>(big, wot, bo, proj, 1024, 1024);
    ln_res<<<2048, 256, 0, stream>>>(xb, proj, ln1g, ln1b, cls);
    gemm8p<2><<<384, 512, 131072, stream>>>(xb, w1t, b1f, big, nullptr, nullptr, 3072, 1024);
    gemm4r<<<512, 256, 65536, stream>>>(big, w2t, b2f, proj, 1024, 3072);
    ln_res<<<2048, 256, 0, stream>>>(xb, proj, ln2g, ln2b, cls);
  }
}

// Round 16
// 2188.007 us; speedup vs baseline: 1.0841x; 1.0841x over previous
//
#include <hip/hip_runtime.h>
#include <cstdint>
#include <math.h>

typedef unsigned short u16;
typedef __attribute__((ext_vector_type(4))) float f32x4;
typedef __attribute__((ext_vector_type(8))) __bf16 bf16x8;
typedef __attribute__((ext_vector_type(8))) short short8;

typedef __attribute__((address_space(1))) void g_void;
typedef __attribute__((address_space(3))) void l_void;

__device__ __forceinline__ u16 f2bf(float f) {
  uint32_t u = __builtin_bit_cast(uint32_t, f);
  u += 0x7FFFu + ((u >> 16) & 1u);
  return (u16)(u >> 16);
}
__device__ __forceinline__ float bf2f(u16 h) {
  uint32_t u = ((uint32_t)h) << 16;
  return __builtin_bit_cast(float, u);
}

__device__ __forceinline__ void gload16(const void* g, void* l) {
  __builtin_amdgcn_global_load_lds((g_void*)g, (l_void*)l, 16, 0, 0);
}

// branchless GELU: erf via A&S 7.1.26 (max abs err 1.5e-7)
__device__ __forceinline__ float gelu_exact(float x) {
  float a = x * 0.70710678118654752f;
  float s = fabsf(a);
  float t = __builtin_amdgcn_rcpf(fmaf(0.3275911f, s, 1.0f));
  float p = fmaf(fmaf(fmaf(fmaf(1.061405429f, t, -1.453152027f), t, 1.421413741f), t,
                      -0.284496736f), t, 0.254829592f);
  p *= t;
  float e = __expf(-s * s);
  float er = fmaf(-p, e, 1.0f);
  er = copysignf(er, a);
  return 0.5f * x * (1.0f + er);
}

// ---------------- weight transpose + bf16 convert: Wt[n][k] = W[k][n] ----------------
__global__ void transpose_w(const float* __restrict__ W, u16* __restrict__ Wt, int K, int N) {
  __shared__ float t[32][33];
  const int nb = blockIdx.x * 32, kb = blockIdx.y * 32;
  const int tx = threadIdx.x, ty = threadIdx.y;
#pragma unroll
  for (int i = 0; i < 32; i += 8)
    t[ty + i][tx] = W[(size_t)(kb + ty + i) * N + nb + tx];
  __syncthreads();
#pragma unroll
  for (int i = 0; i < 32; i += 8)
    Wt[(size_t)(nb + ty + i) * K + kb + tx] = f2bf(t[tx][ty + i]);
}

// ---------------- embedding (bf16 residual stream) ----------------
__global__ void embed_k(const int* __restrict__ z, const int* __restrict__ hgs,
                        const float* __restrict__ ae, const float* __restrict__ ne,
                        u16* __restrict__ xb) {
  const int row = blockIdx.x;
  const int b = row >> 7, tl = row & 127;
  int ia = 1, in_ = 0;
  if (tl > 0) { ia = z[b * 127 + tl - 1] + 2; in_ = hgs[b * 127 + tl - 1] + 2; }
  const float* ar = ae + (size_t)ia * 1024;
  const float* nr = ne + (size_t)in_ * 1024;
  for (int c = threadIdx.x; c < 1024; c += 256)
    xb[(size_t)row * 1024 + c] = f2bf(ar[c] + nr[c]);
}

// ------- attention bias mask*8 precompute, layout [bh][col lk:128][row lq:128] bf16 -----
__global__ void mask_k(const float* __restrict__ pos, const float* __restrict__ demb,
                       u16* __restrict__ mask) {
  __shared__ float edges[85];
  __shared__ float dhT[16 * 86];  // [h][c], pre-scaled by 8
  const int blk = blockIdx.x;
  const int b = blk >> 7, lk = blk & 127;
  const int lq = threadIdx.x;  // 128 threads
  if (lq < 85) {
    double e = 0.75 + 0.05 * (double)lq;
    float ef = (float)e;
    if (lq == 0) ef = -1.0f; else if (lq == 1) ef = 0.0f; else if (lq == 2) ef = 0.01f;
    edges[lq] = ef;
  }
  for (int i = lq; i < 16 * 86; i += 128) {
    const int h = i / 86, c = i - h * 86;
    float v = (c == 0) ? -INFINITY : demb[c * 16 + h] * 8.0f;
    dhT[i] = v;
  }
  __syncthreads();
  int c;
  if (lq == 0 || lk == 0) {
    c = 1;
  } else {
    const float* pi = pos + ((size_t)b * 127 + lq - 1) * 3;
    const float* pj = pos + ((size_t)b * 127 + lk - 1) * 3;
    const float dx = pi[0] - pj[0], dy = pi[1] - pj[1], dz = pi[2] - pj[2];
    const float d = sqrtf(dx * dx + dy * dy + dz * dz);
    int cnt = 0;
#pragma unroll
    for (int k2 = 0; k2 < 85; ++k2) cnt += (edges[k2] <= d) ? 1 : 0;
    c = cnt;
  }
#pragma unroll
  for (int h = 0; h < 16; ++h)
    mask[((size_t)(b * 16 + h) << 14) + lk * 128 + lq] = f2bf(dhT[h * 86 + c]);
}

// ------- big GEMM: 512 thr, 8 waves (4Mx2N), BM=256 BN=128 BK=32, wave-tile 64x64 -----
// 3-buf depth-2 counted vmcnt; st-swizzled LDS; 2 blocks/CU -> 4 waves/SIMD.
// TWO-PHASE K-step (R13-measured-best).
// MODE 0: qkv scatter -> Q(B,H,L,d) K(B,H,L,d) V(B,H,d,L)   MODE 2: gelu bf16
template <int MODE>
__launch_bounds__(512, 4)
__global__ void gemmS(const u16* __restrict__ A, const u16* __restrict__ Bt,
                      const float* __restrict__ bias,
                      u16* __restrict__ O0, u16* __restrict__ O1, u16* __restrict__ O2,
                      int N, int K) {
  extern __shared__ char lds[];
  constexpr int SLAB = 24576;
  const int tid = threadIdx.x;
  const int w = tid >> 6, l = tid & 63;
  const int wr = w >> 1, wc = w & 1;
  const int nwg = gridDim.x;
  const int wg = (blockIdx.x & 7) * (nwg >> 3) + (blockIdx.x >> 3);
  const int ntn = N >> 7;
  const int bm = wg / ntn, bn = wg - (wg / ntn) * ntn;
  const int NT = K >> 5;

  const int colc = ((((l & 3) << 4) ^ (((l >> 2) & 8) << 2)) >> 1);
  const u16* Ag = A + (size_t)(bm * 256 + w * 16 + (l >> 2)) * K + colc;
  const u16* Bg = Bt + (size_t)(bn * 128 + w * 16 + (l >> 2)) * K + colc;
  const int ldst = w << 10;

  const int lo = ((l & 15) << 6) + (((l >> 4) << 4) ^ ((l & 8) << 2));

  f32x4 acc[4][4];
#pragma unroll
  for (int m = 0; m < 4; ++m)
#pragma unroll
    for (int n = 0; n < 4; ++n) acc[m][n] = f32x4{0.f, 0.f, 0.f, 0.f};

  char* p0 = lds;
  char* p1 = lds + SLAB;
  char* p2 = lds + 2 * SLAB;

  {
    gload16(Ag + 0, p0 + ldst);
    gload16(Ag + (size_t)128 * K + 0, p0 + 8192 + ldst);
    gload16(Bg + 0, p0 + 16384 + ldst);
    gload16(Ag + 32, p1 + ldst);
    gload16(Ag + (size_t)128 * K + 32, p1 + 8192 + ldst);
    gload16(Bg + 32, p1 + 16384 + ldst);
  }
  asm volatile("s_waitcnt vmcnt(3)" ::: "memory");
  __builtin_amdgcn_s_barrier();

  for (int t = 0; t < NT; ++t) {
    const bool pre = (t + 2 < NT);
    const int kb2 = (t + 2) << 5;
    const char* ab = p0 + (wr << 12);
    const char* bb = p0 + 16384 + (wc << 12);
    bf16x8 af[4], bf[4];
#pragma unroll
    for (int m = 0; m < 4; ++m) af[m] = *(const bf16x8*)(ab + (m << 10) + lo);
#pragma unroll
    for (int n = 0; n < 2; ++n) bf[n] = *(const bf16x8*)(bb + (n << 10) + lo);
    if (pre) {
      gload16(Ag + kb2, p2 + ldst);
      gload16(Ag + (size_t)128 * K + kb2, p2 + 8192 + ldst);
    }
    __builtin_amdgcn_s_barrier();
    asm volatile("s_waitcnt lgkmcnt(0)" ::: "memory");
    __builtin_amdgcn_s_setprio(1);
#pragma unroll
    for (int m = 0; m < 4; ++m)
#pragma unroll
      for (int n = 0; n < 2; ++n)
        acc[m][n] = __builtin_amdgcn_mfma_f32_16x16x32_bf16(af[m], bf[n], acc[m][n], 0, 0, 0);
    __builtin_amdgcn_s_setprio(0);
    __builtin_amdgcn_s_barrier();
#pragma unroll
    for (int n = 2; n < 4; ++n) bf[n] = *(const bf16x8*)(bb + (n << 10) + lo);
    if (pre) gload16(Bg + kb2, p2 + 16384 + ldst);
    __builtin_amdgcn_s_barrier();
    asm volatile("s_waitcnt lgkmcnt(0)" ::: "memory");
    __builtin_amdgcn_s_setprio(1);
#pragma unroll
    for (int m = 0; m < 4; ++m)
#pragma unroll
      for (int n = 2; n < 4; ++n)
        acc[m][n] = __builtin_amdgcn_mfma_f32_16x16x32_bf16(af[m], bf[n], acc[m][n], 0, 0, 0);
    __builtin_amdgcn_s_setprio(0);
    if (pre) asm volatile("s_waitcnt vmcnt(3)" ::: "memory");
    else     asm volatile("s_waitcnt vmcnt(0)" ::: "memory");
    __builtin_amdgcn_s_barrier();
    char* tmp = p0; p0 = p1; p1 = p2; p2 = tmp;
  }

  const int fr = l & 15, fq = l >> 4;
  const int colb = bn * 128 + wc * 64;
  const int rowb = bm * 256 + wr * 64;
  float bv[4];
#pragma unroll
  for (int n = 0; n < 4; ++n) bv[n] = bias[colb + n * 16 + fr];
  const int region = colb >> 10;

#pragma unroll
  for (int m = 0; m < 4; ++m) {
#pragma unroll
    for (int n = 0; n < 4; ++n) {
      const int col = colb + n * 16 + fr;
      if (MODE == 0 && region == 2) {
        const int row0_ = rowb + m * 16 + fq * 4;
        const int bI = row0_ >> 7, tl0 = row0_ & 127;
        const int c = col & 1023, h = c >> 6, d = c & 63;
        ushort4 pk;
        pk.x = f2bf(acc[m][n][0] + bv[n]);
        pk.y = f2bf(acc[m][n][1] + bv[n]);
        pk.z = f2bf(acc[m][n][2] + bv[n]);
        pk.w = f2bf(acc[m][n][3] + bv[n]);
        *(ushort4*)&O2[(((size_t)bI * 16 + h) * 64 + d) * 128 + tl0] = pk;
      } else {
#pragma unroll
        for (int j = 0; j < 4; ++j) {
          const int row = rowb + m * 16 + fq * 4 + j;
          float v = acc[m][n][j] + bv[n];
          if (MODE == 2) v = gelu_exact(v);
          if (MODE == 0) {
            const int bI = row >> 7, tl = row & 127;
            const int c = col & 1023, h = c >> 6, d = c & 63;
            if (region == 0) O0[(((size_t)bI * 16 + h) * 128 + tl) * 64 + d] = f2bf(v);
            else             O1[(((size_t)bI * 16 + h) * 128 + tl) * 64 + d] = f2bf(v);
          } else {
            O0[(size_t)row * N + col] = f2bf(v);
          }
        }
      }
    }
  }
}

// ------- small GEMM (N=1024): ring-4 depth-3, unrolled (compile-time LDS offsets) ------
// 256 thr, 4 waves, BM=BN=128, BK=32; LDS 4 x 16KB = 64KB -> 2 blocks/CU. NT % 4 == 0.
__launch_bounds__(256, 2)
__global__ void gemm4r(const u16* __restrict__ A, const u16* __restrict__ Bt,
                       const float* __restrict__ bias, u16* __restrict__ O,
                       int N, int K) {
  extern __shared__ char lds[];
  const int tid = threadIdx.x;
  const int w = tid >> 6, l = tid & 63;
  const int wr = w >> 1, wc = w & 1;
  const int nwg = gridDim.x;
  const int wg = (blockIdx.x & 7) * (nwg >> 3) + (blockIdx.x >> 3);
  const int ntn = N >> 7;
  const int bm = wg / ntn, bn = wg - (wg / ntn) * ntn;
  const int NT = K >> 5;  // 32 or 96, divisible by 4

  const int colc = ((((l & 3) << 4) ^ (((l >> 2) & 8) << 2)) >> 1);
  const u16* Ag = A + (size_t)(bm * 128 + w * 16 + (l >> 2)) * K + colc;
  const u16* Bg = Bt + (size_t)(bn * 128 + w * 16 + (l >> 2)) * K + colc;
  const int ldst = w << 10;

  auto stage = [&](int t) {
    char* buf = lds + ((t & 3) << 14);
    const int kb = t << 5;
    gload16(Ag + kb, buf + ldst);
    gload16(Ag + (size_t)64 * K + kb, buf + 4096 + ldst);
    gload16(Bg + kb, buf + 8192 + ldst);
    gload16(Bg + (size_t)64 * K + kb, buf + 12288 + ldst);
  };

  const int lo = ((l & 15) << 6) + (((l >> 4) << 4) ^ ((l & 8) << 2));

  f32x4 acc[4][4];
#pragma unroll
  for (int m = 0; m < 4; ++m)
#pragma unroll
    for (int n = 0; n < 4; ++n) acc[m][n] = f32x4{0.f, 0.f, 0.f, 0.f};

  auto compute = [&](int bi) {
    const char* ab = lds + (bi << 14) + (wr << 12);
    const char* bb = lds + (bi << 14) + 8192 + (wc << 12);
    bf16x8 af[4], bf[4];
#pragma unroll
    for (int m = 0; m < 4; ++m) af[m] = *(const bf16x8*)(ab + (m << 10) + lo);
#pragma unroll
    for (int n = 0; n < 4; ++n) bf[n] = *(const bf16x8*)(bb + (n << 10) + lo);
    __builtin_amdgcn_s_setprio(1);
#pragma unroll
    for (int m = 0; m < 4; ++m)
#pragma unroll
      for (int n = 0; n < 4; ++n)
        acc[m][n] = __builtin_amdgcn_mfma_f32_16x16x32_bf16(af[m], bf[n], acc[m][n], 0, 0, 0);
    __builtin_amdgcn_s_setprio(0);
  };

  stage(0); stage(1); stage(2);
  asm volatile("s_waitcnt vmcnt(8)" ::: "memory");
  __builtin_amdgcn_s_barrier();

  for (int t4 = 0; t4 + 4 < NT; t4 += 4) {
#pragma unroll
    for (int u = 0; u < 4; ++u) {
      stage(t4 + u + 3);
      compute(u);
      asm volatile("s_waitcnt vmcnt(8)" ::: "memory");
      __builtin_amdgcn_s_barrier();
    }
  }
  stage(NT - 1);
  compute(0);
  asm volatile("s_waitcnt vmcnt(8)" ::: "memory");
  __builtin_amdgcn_s_barrier();
  compute(1);
  asm volatile("s_waitcnt vmcnt(4)" ::: "memory");
  __builtin_amdgcn_s_barrier();
  compute(2);
  asm volatile("s_waitcnt vmcnt(0)" ::: "memory");
  __builtin_amdgcn_s_barrier();
  compute(3);

  const int fr = l & 15, fq = l >> 4;
  const int colb = bn * 128 + wc * 64;
  const int rowb = bm * 128 + wr * 64;
  float bv[4];
#pragma unroll
  for (int n = 0; n < 4; ++n) bv[n] = bias[colb + n * 16 + fr];
#pragma unroll
  for (int m = 0; m < 4; ++m)
#pragma unroll
    for (int n = 0; n < 4; ++n) {
      const int col = colb + n * 16 + fr;
#pragma unroll
      for (int j = 0; j < 4; ++j) {
        const int row = rowb + m * 16 + fq * 4 + j;
        O[(size_t)row * N + col] = f2bf(acc[m][n][j] + bv[n]);
      }
    }
}

// ------ fused attention: one block per (b,h); mask*8 as QK^T acc-init ------
__launch_bounds__(256)
__global__ void attn_kernel(const u16* __restrict__ Qg, const u16* __restrict__ Kg,
                            const u16* __restrict__ Vg,
                            const u16* __restrict__ mask,
                            u16* __restrict__ Og) {
  __shared__ u16 QK[2 * 128 * 64];
  __shared__ u16 Vt[64 * 128];
  const int tid = threadIdx.x;
  const int wv = tid >> 6;
  const int l = tid & 63;
  const int bh = blockIdx.x;
  const int b = bh >> 4;

  const char* Qs = (const char*)(Qg + (size_t)bh * 8192);
  const char* Ks = (const char*)(Kg + (size_t)bh * 8192);
  const char* Vs = (const char*)(Vg + (size_t)bh * 8192);
  char* QKb = (char*)QK;
  char* Vtb = (char*)Vt;
#pragma unroll
  for (int it = 0; it < 4; ++it) {
    const int r = it * 32 + (tid >> 3);
    const int cb = (tid & 7) * 16;
    const int sw = cb ^ ((r & 7) << 4);
    *(uint4*)(QKb + r * 128 + sw) = *(const uint4*)(Qs + r * 128 + cb);
    *(uint4*)(QKb + 16384 + r * 128 + sw) = *(const uint4*)(Ks + r * 128 + cb);
  }
#pragma unroll
  for (int it = 0; it < 4; ++it) {
    const int r = it * 16 + (tid >> 4);
    const int cb = (tid & 15) * 16;
    const int sw = cb ^ ((r & 7) << 4);
    *(uint4*)(Vtb + r * 256 + sw) = *(const uint4*)(Vs + r * 256 + cb);
  }

  const u16* m8 = mask + ((size_t)bh << 14);
  f32x4 s[2][8];
#pragma unroll
  for (int m = 0; m < 2; ++m) {
    const int r0 = wv * 32 + m * 16 + (l >> 4) * 4;
#pragma unroll
    for (int n = 0; n < 8; ++n) {
      const int col = n * 16 + (l & 15);
      const ushort4 mv = *(const ushort4*)(m8 + col * 128 + r0);
      s[m][n] = f32x4{bf2f(mv.x), bf2f(mv.y), bf2f(mv.z), bf2f(mv.w)};
    }
  }
  __syncthreads();

#pragma unroll
  for (int kk = 0; kk < 2; ++kk) {
    bf16x8 qa[2], kb[8];
#pragma unroll
    for (int m = 0; m < 2; ++m) {
      const int qr = wv * 32 + m * 16 + (l & 15);
      qa[m] = *(const bf16x8*)(QKb + qr * 128 + ((kk * 64 + (l >> 4) * 16) ^ ((qr & 7) << 4)));
    }
#pragma unroll
    for (int n = 0; n < 8; ++n) {
      const int kr = n * 16 + (l & 15);
      kb[n] = *(const bf16x8*)(QKb + 16384 + kr * 128 + ((kk * 64 + (l >> 4) * 16) ^ ((kr & 7) << 4)));
    }
#pragma unroll
    for (int m = 0; m < 2; ++m)
#pragma unroll
      for (int n = 0; n < 8; ++n)
        s[m][n] = __builtin_amdgcn_mfma_f32_16x16x32_bf16(qa[m], kb[n], s[m][n], 0, 0, 0);
  }

  float rinv[2][4];
#pragma unroll
  for (int m = 0; m < 2; ++m) {
#pragma unroll
    for (int j = 0; j < 4; ++j) {
      float vals[8];
#pragma unroll
      for (int n = 0; n < 8; ++n)
        vals[n] = s[m][n][j] * 0.125f;
      float mx = vals[0];
#pragma unroll
      for (int n = 1; n < 8; ++n) mx = fmaxf(mx, vals[n]);
#pragma unroll
      for (int o = 1; o < 16; o <<= 1) mx = fmaxf(mx, __shfl_xor(mx, o, 64));
      float sum = 0.f;
#pragma unroll
      for (int n = 0; n < 8; ++n) { vals[n] = expf(vals[n] - mx); sum += vals[n]; }
#pragma unroll
      for (int o = 1; o < 16; o <<= 1) sum += __shfl_xor(sum, o, 64);
      rinv[m][j] = 1.f / sum;
#pragma unroll
      for (int n = 0; n < 8; ++n) s[m][n][j] = vals[n];
    }
  }
  __syncthreads();  // all waves done reading Q/K before P overwrites that LDS
  char* Pb = QKb + wv * 8192;
#pragma unroll
  for (int m = 0; m < 2; ++m)
#pragma unroll
    for (int n = 0; n < 8; ++n)
#pragma unroll
      for (int j = 0; j < 4; ++j) {
        const int pr = m * 16 + (l >> 4) * 4 + j;
        const int pc = (n * 16 + (l & 15)) * 2;
        *(u16*)(Pb + pr * 256 + (pc ^ ((pr & 7) << 4))) = f2bf(s[m][n][j]);
      }
  // no barrier: P region is per-wave private; in-wave ds ordering via lgkmcnt

  f32x4 o_[2][4];
#pragma unroll
  for (int m = 0; m < 2; ++m)
#pragma unroll
    for (int n = 0; n < 4; ++n) o_[m][n] = f32x4{0.f, 0.f, 0.f, 0.f};
#pragma unroll
  for (int ks = 0; ks < 4; ++ks) {
    bf16x8 pa[2], vb[4];
#pragma unroll
    for (int m = 0; m < 2; ++m) {
      const int pr = m * 16 + (l & 15);
      pa[m] = *(const bf16x8*)(Pb + pr * 256 + ((ks * 64 + (l >> 4) * 16) ^ ((pr & 7) << 4)));
    }
#pragma unroll
    for (int n = 0; n < 4; ++n) {
      const int vr = n * 16 + (l & 15);
      vb[n] = *(const bf16x8*)(Vtb + vr * 256 + ((ks * 64 + (l >> 4) * 16) ^ ((vr & 7) << 4)));
    }
#pragma unroll
    for (int m = 0; m < 2; ++m)
#pragma unroll
      for (int n = 0; n < 4; ++n)
        o_[m][n] = __builtin_amdgcn_mfma_f32_16x16x32_bf16(pa[m], vb[n], o_[m][n], 0, 0, 0);
  }
  const int h = bh & 15;
#pragma unroll
  for (int m = 0; m < 2; ++m)
#pragma unroll
    for (int n = 0; n < 4; ++n)
#pragma unroll
      for (int j = 0; j < 4; ++j) {
        const int lo2 = wv * 32 + m * 16 + (l >> 4) * 4 + j;
        const int d = n * 16 + (l & 15);
        Og[((size_t)b * 128 + lo2) * 1024 + h * 64 + d] = f2bf(o_[m][n][j] * rinv[m][j]);
      }
}

// ---------------- residual + LayerNorm, bf16 stream, vectorized ----------------
__launch_bounds__(256)
__global__ void ln_res(u16* __restrict__ xb, const u16* __restrict__ o,
                       const float* __restrict__ gam, const float* __restrict__ bet,
                       float* __restrict__ cls_out) {
  const int row = blockIdx.x * 4 + (threadIdx.x >> 6);
  const int l = threadIdx.x & 63;
  const size_t base = (size_t)row * 1024 + l * 16;
  const int c0 = l * 16;
  float v[16], gv[16], bb[16];
  const short8 xa = *(const short8*)(xb + base);
  const short8 xc = *(const short8*)(xb + base + 8);
  const short8 oa = *(const short8*)(o + base);
  const short8 oc = *(const short8*)(o + base + 8);
#pragma unroll
  for (int i = 0; i < 4; ++i) {
    *(float4*)&gv[i * 4] = *(const float4*)(gam + c0 + i * 4);
    *(float4*)&bb[i * 4] = *(const float4*)(bet + c0 + i * 4);
  }
  float s = 0.f, sq = 0.f;
#pragma unroll
  for (int i = 0; i < 8; ++i) {
    v[i] = bf2f((u16)xa[i]) + bf2f((u16)oa[i]);
    v[i + 8] = bf2f((u16)xc[i]) + bf2f((u16)oc[i]);
  }
#pragma unroll
  for (int i = 0; i < 16; ++i) { s += v[i]; sq += v[i] * v[i]; }
#pragma unroll
  for (int off = 1; off < 64; off <<= 1) {
    s += __shfl_xor(s, off, 64);
    sq += __shfl_xor(sq, off, 64);
  }
  const float mean = s * (1.f / 1024.f);
  const float var = sq * (1.f / 1024.f) - mean * mean;
  const float rstd = rsqrtf(var + 1e-5f);
  short8 ra, rc;
#pragma unroll
  for (int i = 0; i < 8; ++i) {
    const float ya = (v[i] - mean) * rstd * gv[i] + bb[i];
    const float yc = (v[i + 8] - mean) * rstd * gv[i + 8] + bb[i + 8];
    ra[i] = (short)f2bf(ya);
    rc[i] = (short)f2bf(yc);
    if ((row & 127) == 0) {
      cls_out[(size_t)(row >> 7) * 1024 + c0 + i] = ya;
      cls_out[(size_t)(row >> 7) * 1024 + c0 + 8 + i] = yc;
    }
  }
  *(short8*)(xb + base) = ra;
  *(short8*)(xb + base + 8) = rc;
}

extern "C" void kernel_launch(void* const* d_in, const int* in_sizes, int n_in,
                              void* d_out, int out_size, void* d_ws, size_t ws_size,
                              hipStream_t stream) {
  const int* z = (const int*)d_in[0];
  const int* hgs = (const int*)d_in[1];
  const float* pos = (const float*)d_in[2];
  const float* atoms_emb = (const float*)d_in[4];
  const float* neigh_emb = (const float*)d_in[5];
  const float* dist_emb = (const float*)d_in[6];
  const float* Wqkv = (const float*)d_in[7];
  const float* bqkv = (const float*)d_in[8];
  const float* Wo = (const float*)d_in[9];
  const float* bo = (const float*)d_in[10];
  const float* W1 = (const float*)d_in[11];
  const float* b1f = (const float*)d_in[12];
  const float* W2 = (const float*)d_in[13];
  const float* b2f = (const float*)d_in[14];
  const float* ln1g = (const float*)d_in[15];
  const float* ln1b = (const float*)d_in[16];
  const float* ln2g = (const float*)d_in[17];
  const float* ln2b = (const float*)d_in[18];

  size_t off = 0;
  char* wsb = (char*)d_ws;
  auto alc = [&](size_t bytes) { void* p = wsb + off; off += (bytes + 255) & ~(size_t)255; return p; };
  u16* xb = (u16*)alc(8192ull * 1024 * 2);
  u16* q = (u16*)alc(8192ull * 1024 * 2);
  u16* k = (u16*)alc(8192ull * 1024 * 2);
  u16* v = (u16*)alc(8192ull * 1024 * 2);
  u16* proj = (u16*)alc(8192ull * 1024 * 2);
  u16* big = (u16*)alc(8192ull * 3072 * 2);
  u16* wqkvt = (u16*)alc(3072ull * 1024 * 2);
  u16* wot = (u16*)alc(1024ull * 1024 * 2);
  u16* w1t = (u16*)alc(3072ull * 1024 * 2);
  u16* w2t = (u16*)alc(1024ull * 3072 * 2);
  u16* mask = (u16*)alc(64ull * 16 * 128 * 128 * 2);

  hipFuncSetAttribute((const void*)gemmS<0>, hipFuncAttributeMaxDynamicSharedMemorySize, 73728);
  hipFuncSetAttribute((const void*)gemmS<2>, hipFuncAttributeMaxDynamicSharedMemorySize, 73728);
  hipFuncSetAttribute((const void*)gemm4r, hipFuncAttributeMaxDynamicSharedMemorySize, 65536);

  transpose_w<<<dim3(96, 32), dim3(32, 8), 0, stream>>>(Wqkv, wqkvt, 1024, 3072);
  transpose_w<<<dim3(32, 32), dim3(32, 8), 0, stream>>>(Wo, wot, 1024, 1024);
  transpose_w<<<dim3(96, 32), dim3(32, 8), 0, stream>>>(W1, w1t, 1024, 3072);
  transpose_w<<<dim3(32, 96), dim3(32, 8), 0, stream>>>(W2, w2t, 3072, 1024);
  embed_k<<<8192, 256, 0, stream>>>(z, hgs, atoms_emb, neigh_emb, xb);
  mask_k<<<8192, 128, 0, stream>>>(pos, dist_emb, mask);

  float* cls = (float*)d_out;
  for (int layer = 0; layer < 8; ++layer) {
    gemmS<0><<<768, 512, 73728, stream>>>(xb, wqkvt, bqkv, q, k, v, 3072, 1024);
    attn_kernel<<<1024, 256, 0, stream>>>(q, k, v, mask, big);
    gemm4r<<<512, 256, 65536, stream>>>(big, wot, bo, proj, 1024, 1024);
    ln_res<<<2048, 256, 0, stream>>>(xb, proj, ln1g, ln1b, cls);
    gemmS<2><<<768, 512, 73728, stream>>>(xb, w1t, b1f, big, nullptr, nullptr, 3072, 1024);
    gemm4r<<<512, 256, 65536, stream>>>(big, w2t, b2f, proj, 1024, 3072);
    ln_res<<<2048, 256, 0, stream>>>(xb, proj, ln2g, ln2b, cls);
  }
}